// Round 20
// baseline (51.645 us; speedup 1.0000x reference)
//
#include <hip/hip_runtime.h>
#include <hip/hip_fp16.h>
#include <math.h>

#define B_ 16
#define F_ 256
#define T_ 2048
#define K_ 20
#define OUTK 21
#define NPAIR 10
#define PT 16    // prep t-tile (16 -> 18.6 KB LDS -> 8 blocks/CU)

typedef float v2f __attribute__((ext_vector_type(2)));

#if __has_builtin(__builtin_amdgcn_cvt_pk_f32_fp8) && __has_builtin(__builtin_amdgcn_cvt_pk_fp8_f32)
#define HW_FP8 1
#else
#define HW_FP8 0
#endif

#if !HW_FP8
// fallback e4m3 (OCP) decode/encode — only compiled if HW cvt builtins absent
__device__ __forceinline__ float dec_fp8(unsigned v) {
    unsigned s = (v >> 7) & 1, e = (v >> 3) & 15, m = v & 7;
    float r = e ? __uint_as_float(((e + 120u) << 23) | (m << 20))
                : (float)m * 0.001953125f;  // 2^-9
    return s ? -r : r;
}
__device__ __forceinline__ unsigned enc_fp8(float x) {
    unsigned bits = __float_as_uint(x);
    unsigned s = bits >> 31;
    unsigned a = bits & 0x7fffffffu;
    float ax = __uint_as_float(a);
    unsigned r;
    if (ax < 0.015625f) {                      // subnormal (< 2^-6)
        r = (unsigned)(int)(ax * 512.f + 0.5f);
    } else {
        int e = (int)(a >> 23) - 127;
        unsigned m = a & 0x7fffffu;
        unsigned keep = m >> 20, rest = m & 0xFFFFFu;
        keep += (rest > 0x80000u) || (rest == 0x80000u && (keep & 1));
        if (keep == 8) { keep = 0; ++e; }
        r = ((unsigned)(e + 7) << 3) | keep;
    }
    return (s << 7) | r;
}
#endif

__device__ __forceinline__ unsigned pack_fp8x4(float a0, float a1, float a2, float a3) {
#if HW_FP8
    int u = 0;
    u = __builtin_amdgcn_cvt_pk_fp8_f32(a0, a1, u, false);
    u = __builtin_amdgcn_cvt_pk_fp8_f32(a2, a3, u, true);
    return (unsigned)u;
#else
    return enc_fp8(a0) | (enc_fp8(a1) << 8) | (enc_fp8(a2) << 16) | (enc_fp8(a3) << 24);
#endif
}
template <bool HI>
__device__ __forceinline__ v2f unpk_fp8(unsigned u) {
#if HW_FP8
    return __builtin_amdgcn_cvt_pk_f32_fp8((int)u, HI);
#else
    v2f r; unsigned x = HI ? (u >> 16) : u;
    r[0] = dec_fp8(x & 0xFF); r[1] = dec_fp8((x >> 8) & 0xFF);
    return r;
#endif
}

// Prep: r16 structure with a HALVED tile (16 t). 18.6 KB LDS -> 8 blocks/CU,
// doubling resident blocks (prep is memory-parallelism-bound: r13 2blk=42.9us
// -> r16 4blk=24.2us scaled ~2x). launch_bounds(256,8) keeps VGPR<=64 so LDS
// sets occupancy.
__global__ __launch_bounds__(256, 8) void prep_kernel(
    const float* __restrict__ z, const float* __restrict__ c,
    unsigned char* __restrict__ zf8, unsigned char* __restrict__ cf8)
{
    __shared__ float tile[256][PT + 1];  // 256 f x 16 t, +1 pad
    __shared__ float ps[PT][17];         // 16 partial sums per column, +1 pad
    __shared__ float sc[PT];             // per-column 1/norm
    int which = blockIdx.z;
    unsigned char* dst = which ? cf8 : zf8;

    int b  = blockIdx.y;
    int t0 = blockIdx.x * PT;

    if (which == 0) {
        // z: float4 loads — 4 t-quads/row, 64 f-rows per instruction, 4 iters
        const float* zb = z + (size_t)b * F_ * T_ + t0;
        int q  = threadIdx.x & 3;
        int fo = threadIdx.x >> 2;
#pragma unroll
        for (int i = 0; i < 4; ++i) {
            int f = i * 64 + fo;
            float4 v = *(const float4*)(zb + (size_t)f * T_ + 4 * q);
            tile[f][4 * q + 0] = v.x;
            tile[f][4 * q + 1] = v.y;
            tile[f][4 * q + 2] = v.z;
            tile[f][4 * q + 3] = v.w;
        }
    } else {
        // c: scalar loads (rows unalignable, Lsrc = 2049), drop start token
        const float* cb = c + (size_t)b * F_ * (T_ + 1);
        int tl = threadIdx.x & 15;
        int fl = threadIdx.x >> 4;
#pragma unroll
        for (int i = 0; i < 16; ++i) {
            int f = i * 16 + fl;
            tile[f][tl] = cb[(size_t)f * (T_ + 1) + (t0 + tl + 1)];
        }
    }
    __syncthreads();
    // parallel norm: thread (col, grp) sums 16 f-values; fold by 16 threads
    {
        int col = threadIdx.x & 15, grp = threadIdx.x >> 4;
        float s = 0.f;
#pragma unroll 4
        for (int qq = 0; qq < 16; ++qq) {
            float v = tile[grp * 16 + qq][col];
            s = fmaf(v, v, s);
        }
        ps[col][grp] = s;
    }
    __syncthreads();
    if (threadIdx.x < PT) {
        float s = 0.f;
#pragma unroll
        for (int g = 0; g < 16; ++g) s += ps[threadIdx.x][g];
        float n = sqrtf(s);
        sc[threadIdx.x] = (n > 0.f) ? (1.0f / n) : 0.f;
    }
    __syncthreads();
    // write: lane j packs 4 values -> dword; 64 lanes = 256 B row; 4 rows/iter
    {
        int j = threadIdx.x & 63, r4 = threadIdx.x >> 6;
#pragma unroll
        for (int it = 0; it < PT / 4; ++it) {
            int row = it * 4 + r4;
            float s = sc[row];
            unsigned u = pack_fp8x4(tile[2 * j][row] * s, tile[2 * j + 1][row] * s,
                                    tile[2 * j + 128][row] * s, tile[2 * j + 129][row] * s);
            ((unsigned*)(dst + ((size_t)b * T_ + t0 + row) * F_))[j] = u;
        }
    }
}

// Sum within each 32-lane half (pure VALU DPP). Valid in lane 31 (lo) / 63 (hi).
__device__ __forceinline__ float dpp_half_sum(float x) {
    x += __int_as_float(__builtin_amdgcn_mov_dpp(__float_as_int(x), 0x111, 0xF, 0xF, true)); // row_shr:1
    x += __int_as_float(__builtin_amdgcn_mov_dpp(__float_as_int(x), 0x112, 0xF, 0xF, true)); // row_shr:2
    x += __int_as_float(__builtin_amdgcn_mov_dpp(__float_as_int(x), 0x114, 0xF, 0xF, true)); // row_shr:4
    x += __int_as_float(__builtin_amdgcn_mov_dpp(__float_as_int(x), 0x118, 0xF, 0xF, true)); // row_shr:8
    x += __int_as_float(__builtin_amdgcn_mov_dpp(__float_as_int(x), 0x142, 0xF, 0xF, true)); // row_bcast:15
    return x;
}

// Sim: identical to r16 (measured 18.2 us, L2-random-request bound).
__global__ __launch_bounds__(256, 8) void sim_kernel(
    const unsigned char* __restrict__ zf8, const unsigned char* __restrict__ cf8,
    const int* __restrict__ inds, float* __restrict__ out)
{
    __shared__ float sd[128];                         // 4 waves x 32 slots
    int i = blockIdx.x;                               // 8192 blocks, 4 waves each
    int b = (i & 7) | ((i >= 4096) ? 8 : 0);          // batch b on XCD b&7 (L2-resident tables)
    int wid = threadIdx.x >> 6;
    int t = (((i >> 3) & 511) << 2) + wid;
    int lane = threadIdx.x & 63;
    int hl = lane & 31;                               // pos within half
    int hi = lane >> 5;                               // which half
    int bt = __builtin_amdgcn_readfirstlane((b << 11) + t);

    const int* myinds = inds + bt * K_;
    int idxv = myinds[(lane < K_) ? lane : 0];        // lane k holds inds[k]

    uint2 zv8 = ((const uint2*)(zf8 + (size_t)bt * F_))[hl];   // own z row (fp8)
    uint2 cv8 = ((const uint2*)(cf8 + (size_t)bt * F_))[hl];   // own c row (fp8)

    const char* tbl8 = (const char*)zf8;
    unsigned zbase8  = (unsigned)(b << 11) * 256u;
    unsigned laneoff = (unsigned)hl * 8u;

    uint2 tv[NPAIR];
#pragma unroll
    for (int p = 0; p < NPAIR; ++p) {
        unsigned ilo = (unsigned)__builtin_amdgcn_readlane(idxv, 2 * p);
        unsigned ihi = (unsigned)__builtin_amdgcn_readlane(idxv, 2 * p + 1);
        unsigned off = zbase8 + (hi ? ihi : ilo) * 256u + laneoff;
        tv[p] = *(const uint2*)(tbl8 + off);
    }

    __builtin_amdgcn_sched_barrier(0);

    float zf[8];
    {
        v2f a01 = unpk_fp8<false>(zv8.x), a23 = unpk_fp8<true>(zv8.x);
        v2f a45 = unpk_fp8<false>(zv8.y), a67 = unpk_fp8<true>(zv8.y);
        zf[0] = a01[0]; zf[1] = a01[1]; zf[2] = a23[0]; zf[3] = a23[1];
        zf[4] = a45[0]; zf[5] = a45[1]; zf[6] = a67[0]; zf[7] = a67[1];
    }

    float dc;
    {
        v2f c01 = unpk_fp8<false>(cv8.x), c23 = unpk_fp8<true>(cv8.x);
        v2f c45 = unpk_fp8<false>(cv8.y), c67 = unpk_fp8<true>(cv8.y);
        float d = zf[0] * c01[0];
        d = fmaf(zf[1], c01[1], d);
        d = fmaf(zf[2], c23[0], d);
        d = fmaf(zf[3], c23[1], d);
        d = fmaf(zf[4], c45[0], d);
        d = fmaf(zf[5], c45[1], d);
        d = fmaf(zf[6], c67[0], d);
        d = fmaf(zf[7], c67[1], d);
        dc = d;
    }

    float dz[NPAIR];
#pragma unroll
    for (int p = 0; p < NPAIR; ++p) {
        v2f t01 = unpk_fp8<false>(tv[p].x), t23 = unpk_fp8<true>(tv[p].x);
        v2f t45 = unpk_fp8<false>(tv[p].y), t67 = unpk_fp8<true>(tv[p].y);
        float d = zf[0] * t01[0];
        d = fmaf(zf[1], t01[1], d);
        d = fmaf(zf[2], t23[0], d);
        d = fmaf(zf[3], t23[1], d);
        d = fmaf(zf[4], t45[0], d);
        d = fmaf(zf[5], t45[1], d);
        d = fmaf(zf[6], t67[0], d);
        d = fmaf(zf[7], t67[1], d);
        dz[p] = d;
    }

    unsigned mb = 0;
#pragma unroll
    for (int p = 0; p < NPAIR; ++p) {
        unsigned long long ball = __ballot(tv[p].x == cv8.x);
        unsigned blo = (unsigned)ball, bhi = (unsigned)(ball >> 32);
        if (blo == 0xFFFFFFFFu || bhi == 0xFFFFFFFFu) {
            bool full = (tv[p].x == cv8.x) && (tv[p].y == cv8.y);
            unsigned long long b2 = __ballot(full);
            if ((unsigned)b2 == 0xFFFFFFFFu)          mb |= 1u << (1 + 2 * p);
            if ((unsigned)(b2 >> 32) == 0xFFFFFFFFu)  mb |= 1u << (2 + 2 * p);
        }
    }

    dc = dpp_half_sum(dc);
#pragma unroll
    for (int p = 0; p < NPAIR; ++p) dz[p] = dpp_half_sum(dz[p]);

    if (hl == 31) {
        if (hi == 0) sd[wid * 32] = dc;
#pragma unroll
        for (int p = 0; p < NPAIR; ++p) sd[wid * 32 + 1 + 2 * p + hi] = dz[p];
    }

    if (lane < OUTK) {
        float v = sd[wid * 32 + lane] * 2.0f;         // / TEMP, TEMP = 0.5
        if ((mb >> lane) & 1u) v = -INFINITY;
        out[(size_t)bt * OUTK + lane] = v;
    }
}

extern "C" void kernel_launch(void* const* d_in, const int* in_sizes, int n_in,
                              void* d_out, int out_size, void* d_ws, size_t ws_size,
                              hipStream_t stream)
{
    const float* z    = (const float*)d_in[0];
    const float* c    = (const float*)d_in[1];
    const int*   inds = (const int*)d_in[2];
    float* out = (float*)d_out;

    char* ws = (char*)d_ws;
    size_t f8_bytes = (size_t)B_ * T_ * F_;                    // 8 MB
    unsigned char* zf8 = (unsigned char*)ws;
    unsigned char* cf8 = (unsigned char*)(ws + f8_bytes);

    dim3 tb(256), tg(T_ / PT, B_, 2);
    prep_kernel<<<tg, tb, 0, stream>>>(z, c, zf8, cf8);
    sim_kernel<<<dim3(B_ * T_ / 4), dim3(256), 0, stream>>>(zf8, cf8, inds, out);
}

// Round 21
// 41.905 us; speedup vs baseline: 1.2324x; 1.2324x over previous
//
#include <hip/hip_runtime.h>
#include <hip/hip_fp16.h>
#include <math.h>

#define B_ 16
#define F_ 256
#define T_ 2048
#define K_ 20
#define OUTK 21
#define NPAIR 10

typedef float v2f __attribute__((ext_vector_type(2)));

#if __has_builtin(__builtin_amdgcn_cvt_pk_f32_fp8) && __has_builtin(__builtin_amdgcn_cvt_pk_fp8_f32)
#define HW_FP8 1
#else
#define HW_FP8 0
#endif

#if !HW_FP8
// fallback e4m3 (OCP) decode/encode — only compiled if HW cvt builtins absent
__device__ __forceinline__ float dec_fp8(unsigned v) {
    unsigned s = (v >> 7) & 1, e = (v >> 3) & 15, m = v & 7;
    float r = e ? __uint_as_float(((e + 120u) << 23) | (m << 20))
                : (float)m * 0.001953125f;  // 2^-9
    return s ? -r : r;
}
__device__ __forceinline__ unsigned enc_fp8(float x) {
    unsigned bits = __float_as_uint(x);
    unsigned s = bits >> 31;
    unsigned a = bits & 0x7fffffffu;
    float ax = __uint_as_float(a);
    unsigned r;
    if (ax < 0.015625f) {                      // subnormal (< 2^-6)
        r = (unsigned)(int)(ax * 512.f + 0.5f);
    } else {
        int e = (int)(a >> 23) - 127;
        unsigned m = a & 0x7fffffu;
        unsigned keep = m >> 20, rest = m & 0xFFFFFu;
        keep += (rest > 0x80000u) || (rest == 0x80000u && (keep & 1));
        if (keep == 8) { keep = 0; ++e; }
        r = ((unsigned)(e + 7) << 3) | keep;
    }
    return (s << 7) | r;
}
#endif

__device__ __forceinline__ unsigned pack_fp8x4(float a0, float a1, float a2, float a3) {
#if HW_FP8
    int u = 0;
    u = __builtin_amdgcn_cvt_pk_fp8_f32(a0, a1, u, false);
    u = __builtin_amdgcn_cvt_pk_fp8_f32(a2, a3, u, true);
    return (unsigned)u;
#else
    return enc_fp8(a0) | (enc_fp8(a1) << 8) | (enc_fp8(a2) << 16) | (enc_fp8(a3) << 24);
#endif
}
template <bool HI>
__device__ __forceinline__ v2f unpk_fp8(unsigned u) {
#if HW_FP8
    return __builtin_amdgcn_cvt_pk_f32_fp8((int)u, HI);
#else
    v2f r; unsigned x = HI ? (u >> 16) : u;
    r[0] = dec_fp8(x & 0xFF); r[1] = dec_fp8((x >> 8) & 0xFF);
    return r;
#endif
}

// Prep v3: 64-t tile, thread owns (t = tid&63, f-quarter q = tid>>6), holds
// its 64 f-values IN REGISTERS (the transpose is free). Every load
// instruction = 256 B contiguous (lanes are consecutive t). Norm via
// 4-accumulator sumsq + tiny LDS fold. Quantize from registers (no re-read),
// write 64 B (4 x uint4) per thread. fp8 row layout = NATURAL f order
// (dword j holds f 4j..4j+3) — both tables share it; dot/equality invariant.
__global__ __launch_bounds__(256) void prep_kernel(
    const float* __restrict__ z, const float* __restrict__ c,
    unsigned char* __restrict__ zf8, unsigned char* __restrict__ cf8)
{
    __shared__ float ps[64][5];   // partial sumsq per t, +1 pad
    __shared__ float sc[64];      // per-t 1/norm
    int which = blockIdx.z;
    const float* src = which ? c : z;
    unsigned char* dst = which ? cf8 : zf8;
    int Lsrc = which ? (T_ + 1) : T_;
    int co   = which;                    // c drops the start token

    int b  = blockIdx.y;
    int t0 = blockIdx.x * 64;
    int t  = threadIdx.x & 63;
    int q  = threadIdx.x >> 6;           // f-quarter (64 f each)

    const float* base = src + ((size_t)b * F_ + (size_t)q * 64) * Lsrc + (t0 + t + co);

    float vals[64];
    float s0 = 0.f, s1 = 0.f, s2 = 0.f, s3 = 0.f;
#pragma unroll
    for (int i = 0; i < 64; i += 4) {
        vals[i]     = base[(size_t)(i)     * Lsrc];
        vals[i + 1] = base[(size_t)(i + 1) * Lsrc];
        vals[i + 2] = base[(size_t)(i + 2) * Lsrc];
        vals[i + 3] = base[(size_t)(i + 3) * Lsrc];
        s0 = fmaf(vals[i],     vals[i],     s0);
        s1 = fmaf(vals[i + 1], vals[i + 1], s1);
        s2 = fmaf(vals[i + 2], vals[i + 2], s2);
        s3 = fmaf(vals[i + 3], vals[i + 3], s3);
    }
    ps[t][q] = (s0 + s1) + (s2 + s3);
    __syncthreads();
    if (threadIdx.x < 64) {
        float s = (ps[threadIdx.x][0] + ps[threadIdx.x][1])
                + (ps[threadIdx.x][2] + ps[threadIdx.x][3]);
        float n = sqrtf(s);
        sc[threadIdx.x] = (n > 0.f) ? (1.0f / n) : 0.f;
    }
    __syncthreads();
    float scale = sc[t];

    unsigned u[16];
#pragma unroll
    for (int j = 0; j < 16; ++j)
        u[j] = pack_fp8x4(vals[4 * j] * scale, vals[4 * j + 1] * scale,
                          vals[4 * j + 2] * scale, vals[4 * j + 3] * scale);
    uint4* orow = (uint4*)(dst + ((size_t)b * T_ + t0 + t) * F_ + (size_t)q * 64);
#pragma unroll
    for (int j4 = 0; j4 < 4; ++j4) {
        uint4 vv = {u[4 * j4], u[4 * j4 + 1], u[4 * j4 + 2], u[4 * j4 + 3]};
        orow[j4] = vv;
    }
}

// Sum within each 32-lane half (pure VALU DPP). Valid in lane 31 (lo) / 63 (hi).
__device__ __forceinline__ float dpp_half_sum(float x) {
    x += __int_as_float(__builtin_amdgcn_mov_dpp(__float_as_int(x), 0x111, 0xF, 0xF, true)); // row_shr:1
    x += __int_as_float(__builtin_amdgcn_mov_dpp(__float_as_int(x), 0x112, 0xF, 0xF, true)); // row_shr:2
    x += __int_as_float(__builtin_amdgcn_mov_dpp(__float_as_int(x), 0x114, 0xF, 0xF, true)); // row_shr:4
    x += __int_as_float(__builtin_amdgcn_mov_dpp(__float_as_int(x), 0x118, 0xF, 0xF, true)); // row_shr:8
    x += __int_as_float(__builtin_amdgcn_mov_dpp(__float_as_int(x), 0x142, 0xF, 0xF, true)); // row_bcast:15
    return x;
}

// Sim: identical to r16 (measured 18.2 us, L2-random-request bound).
__global__ __launch_bounds__(256, 8) void sim_kernel(
    const unsigned char* __restrict__ zf8, const unsigned char* __restrict__ cf8,
    const int* __restrict__ inds, float* __restrict__ out)
{
    __shared__ float sd[128];                         // 4 waves x 32 slots
    int i = blockIdx.x;                               // 8192 blocks, 4 waves each
    int b = (i & 7) | ((i >= 4096) ? 8 : 0);          // batch b on XCD b&7 (L2-resident tables)
    int wid = threadIdx.x >> 6;
    int t = (((i >> 3) & 511) << 2) + wid;
    int lane = threadIdx.x & 63;
    int hl = lane & 31;                               // pos within half
    int hi = lane >> 5;                               // which half
    int bt = __builtin_amdgcn_readfirstlane((b << 11) + t);

    const int* myinds = inds + bt * K_;
    int idxv = myinds[(lane < K_) ? lane : 0];        // lane k holds inds[k]

    uint2 zv8 = ((const uint2*)(zf8 + (size_t)bt * F_))[hl];   // own z row (fp8)
    uint2 cv8 = ((const uint2*)(cf8 + (size_t)bt * F_))[hl];   // own c row (fp8)

    const char* tbl8 = (const char*)zf8;
    unsigned zbase8  = (unsigned)(b << 11) * 256u;
    unsigned laneoff = (unsigned)hl * 8u;

    uint2 tv[NPAIR];
#pragma unroll
    for (int p = 0; p < NPAIR; ++p) {
        unsigned ilo = (unsigned)__builtin_amdgcn_readlane(idxv, 2 * p);
        unsigned ihi = (unsigned)__builtin_amdgcn_readlane(idxv, 2 * p + 1);
        unsigned off = zbase8 + (hi ? ihi : ilo) * 256u + laneoff;
        tv[p] = *(const uint2*)(tbl8 + off);
    }

    __builtin_amdgcn_sched_barrier(0);

    float zf[8];
    {
        v2f a01 = unpk_fp8<false>(zv8.x), a23 = unpk_fp8<true>(zv8.x);
        v2f a45 = unpk_fp8<false>(zv8.y), a67 = unpk_fp8<true>(zv8.y);
        zf[0] = a01[0]; zf[1] = a01[1]; zf[2] = a23[0]; zf[3] = a23[1];
        zf[4] = a45[0]; zf[5] = a45[1]; zf[6] = a67[0]; zf[7] = a67[1];
    }

    float dc;
    {
        v2f c01 = unpk_fp8<false>(cv8.x), c23 = unpk_fp8<true>(cv8.x);
        v2f c45 = unpk_fp8<false>(cv8.y), c67 = unpk_fp8<true>(cv8.y);
        float d = zf[0] * c01[0];
        d = fmaf(zf[1], c01[1], d);
        d = fmaf(zf[2], c23[0], d);
        d = fmaf(zf[3], c23[1], d);
        d = fmaf(zf[4], c45[0], d);
        d = fmaf(zf[5], c45[1], d);
        d = fmaf(zf[6], c67[0], d);
        d = fmaf(zf[7], c67[1], d);
        dc = d;
    }

    float dz[NPAIR];
#pragma unroll
    for (int p = 0; p < NPAIR; ++p) {
        v2f t01 = unpk_fp8<false>(tv[p].x), t23 = unpk_fp8<true>(tv[p].x);
        v2f t45 = unpk_fp8<false>(tv[p].y), t67 = unpk_fp8<true>(tv[p].y);
        float d = zf[0] * t01[0];
        d = fmaf(zf[1], t01[1], d);
        d = fmaf(zf[2], t23[0], d);
        d = fmaf(zf[3], t23[1], d);
        d = fmaf(zf[4], t45[0], d);
        d = fmaf(zf[5], t45[1], d);
        d = fmaf(zf[6], t67[0], d);
        d = fmaf(zf[7], t67[1], d);
        dz[p] = d;
    }

    unsigned mb = 0;
#pragma unroll
    for (int p = 0; p < NPAIR; ++p) {
        unsigned long long ball = __ballot(tv[p].x == cv8.x);
        unsigned blo = (unsigned)ball, bhi = (unsigned)(ball >> 32);
        if (blo == 0xFFFFFFFFu || bhi == 0xFFFFFFFFu) {
            bool full = (tv[p].x == cv8.x) && (tv[p].y == cv8.y);
            unsigned long long b2 = __ballot(full);
            if ((unsigned)b2 == 0xFFFFFFFFu)          mb |= 1u << (1 + 2 * p);
            if ((unsigned)(b2 >> 32) == 0xFFFFFFFFu)  mb |= 1u << (2 + 2 * p);
        }
    }

    dc = dpp_half_sum(dc);
#pragma unroll
    for (int p = 0; p < NPAIR; ++p) dz[p] = dpp_half_sum(dz[p]);

    if (hl == 31) {
        if (hi == 0) sd[wid * 32] = dc;
#pragma unroll
        for (int p = 0; p < NPAIR; ++p) sd[wid * 32 + 1 + 2 * p + hi] = dz[p];
    }

    if (lane < OUTK) {
        float v = sd[wid * 32 + lane] * 2.0f;         // / TEMP, TEMP = 0.5
        if ((mb >> lane) & 1u) v = -INFINITY;
        out[(size_t)bt * OUTK + lane] = v;
    }
}

extern "C" void kernel_launch(void* const* d_in, const int* in_sizes, int n_in,
                              void* d_out, int out_size, void* d_ws, size_t ws_size,
                              hipStream_t stream)
{
    const float* z    = (const float*)d_in[0];
    const float* c    = (const float*)d_in[1];
    const int*   inds = (const int*)d_in[2];
    float* out = (float*)d_out;

    char* ws = (char*)d_ws;
    size_t f8_bytes = (size_t)B_ * T_ * F_;                    // 8 MB
    unsigned char* zf8 = (unsigned char*)ws;
    unsigned char* cf8 = (unsigned char*)(ws + f8_bytes);

    dim3 tb(256), tg(T_ / 64, B_, 2);
    prep_kernel<<<tg, tb, 0, stream>>>(z, c, zf8, cf8);
    sim_kernel<<<dim3(B_ * T_ / 4), dim3(256), 0, stream>>>(zf8, cf8, inds, out);
}